// Round 3
// baseline (2707.894 us; speedup 1.0000x reference)
//
#include <hip/hip_runtime.h>

typedef __bf16 bf16x8 __attribute__((ext_vector_type(8)));
typedef float f32x4 __attribute__((ext_vector_type(4)));
typedef unsigned short ushort4v __attribute__((ext_vector_type(4)));

__device__ __forceinline__ unsigned short f2bf(float f) {
  unsigned int u = __builtin_bit_cast(unsigned int, f);
  u += 0x7FFFu + ((u >> 16) & 1u);   // round-to-nearest-even
  return (unsigned short)(u >> 16);
}
__device__ __forceinline__ float bf2f(unsigned short h) {
  unsigned int u = ((unsigned int)h) << 16;
  return __builtin_bit_cast(float, u);
}

// ---- cast x (f32 -> bf16) ----
__global__ __launch_bounds__(256) void cast_x_kernel(const float* __restrict__ in,
                                                     unsigned short* __restrict__ out, int nvec) {
  int stride = gridDim.x * blockDim.x;
  for (int i = blockIdx.x * blockDim.x + threadIdx.x; i < nvec; i += stride) {
    float4 v = ((const float4*)in)[i];
    ushort4v o = { f2bf(v.x), f2bf(v.y), f2bf(v.z), f2bf(v.w) };
    ((ushort4v*)out)[i] = o;
  }
}

// ---- w [K][Cin][Cout] f32 -> wT [K][Cout][Cin] bf16 ----
__global__ __launch_bounds__(256) void wcast_kernel(const float* __restrict__ w,
                                                    unsigned short* __restrict__ wT, int total) {
  int i = blockIdx.x * blockDim.x + threadIdx.x;
  if (i >= total) return;
  int k = i >> 14, rem = i & 16383;
  int d = rem >> 7, c = rem & 127;
  wT[i] = f2bf(w[(k << 14) + (c << 7) + d]);
}

// ================= counting sort of pairs by bucket (n>>7, k) ==================

__global__ __launch_bounds__(256) void hist_kernel(const int* __restrict__ iout,
                                                   int* __restrict__ counts,
                                                   int P, int M, int K) {
  int stride = gridDim.x * blockDim.x;
  for (int p = blockIdx.x * blockDim.x + threadIdx.x; p < P; p += stride) {
    int n = iout[p];
    int k = p / M;
    atomicAdd(&counts[(n >> 7) * K + k], 1);
  }
}

__global__ __launch_bounds__(256) void scan1_kernel(const int* __restrict__ counts,
                                                    int* __restrict__ segs,
                                                    int* __restrict__ bsums, int NB) {
  __shared__ int s[256];
  int t = threadIdx.x;
  int g = blockIdx.x * 256 + t;
  int c = (g < NB) ? counts[g] : 0;
  s[t] = c;
  __syncthreads();
  #pragma unroll
  for (int off = 1; off < 256; off <<= 1) {
    int v = (t >= off) ? s[t - off] : 0;
    __syncthreads();
    s[t] += v;
    __syncthreads();
  }
  if (g < NB) segs[g] = s[t] - c;
  if (t == 255) bsums[blockIdx.x] = s[t];
}

__global__ __launch_bounds__(512) void scan2_kernel(int* __restrict__ bsums, int nb) {
  __shared__ int s[512];
  int t = threadIdx.x;
  int c = (t < nb) ? bsums[t] : 0;
  s[t] = c;
  __syncthreads();
  #pragma unroll
  for (int off = 1; off < 512; off <<= 1) {
    int v = (t >= off) ? s[t - off] : 0;
    __syncthreads();
    s[t] += v;
    __syncthreads();
  }
  if (t < nb) bsums[t] = s[t] - c;
}

__global__ __launch_bounds__(256) void scan3_kernel(int* __restrict__ segs,
                                                    const int* __restrict__ bsums,
                                                    int* __restrict__ cursor, int NB) {
  int g = blockIdx.x * 256 + threadIdx.x;
  if (g < NB) {
    int v = segs[g] + bsums[blockIdx.x];
    segs[g] = v;
    cursor[g] = v;
  }
}

// rank + scatter: pl[slot] = (in_idx << 7) | (out_row & 127)
__global__ __launch_bounds__(256) void rankscatter_kernel(
    const int* __restrict__ iin, const int* __restrict__ iout,
    int* __restrict__ cursor, unsigned int* __restrict__ pl,
    int P, int M, int K) {
  int stride = gridDim.x * blockDim.x;
  for (int p = blockIdx.x * blockDim.x + threadIdx.x; p < P; p += stride) {
    int n = iout[p];
    int k = p / M;
    int key = (n >> 7) * K + k;
    int slot = atomicAdd(&cursor[key], 1);
    pl[slot] = ((unsigned int)iin[p] << 7) | (unsigned int)(n & 127);
  }
}

// ========== output-stationary sparse conv: LDS f32 accumulator, no barriers ====
// grid: NB=ceil(N/128) blocks, 256 threads (4 waves). Wave wv owns output cols
// [wv*32, wv*32+32). B (w[k] col slice) in registers; A gathered per-lane from
// global (L2/L3-resident); C accumulated into LDS via ds_add_f32.
// Epilogue fuses BN-stats (sum/sumsq atomics) + acc writeout.
template<bool BF16A>
__global__ __launch_bounds__(256) void spconv_os(
    const unsigned short* __restrict__ xb, const unsigned short* __restrict__ wT,
    const unsigned int* __restrict__ pl, const int* __restrict__ segs,
    void* __restrict__ accg, float* __restrict__ stats,
    int N, int K, int P, int BUCKETS)
{
  __shared__ float accs[128 * 128];
  const int b = blockIdx.x, t = threadIdx.x;
  const int wv = t >> 6, l = t & 63;
  const int l16 = l & 15, lg = l >> 4;

  for (int j = t; j < 128 * 128; j += 256) accs[j] = 0.f;
  __syncthreads();

  for (int k = 0; k < K; ++k) {
    int idx = b * K + k;
    int sbeg = segs[idx];
    int send = (idx + 1 < BUCKETS) ? segs[idx + 1] : P;
    int nt = send - sbeg;
    if (nt <= 0) continue;

    // B fragments in registers: cols (wv*2+ctl)*16 + l16, k-slices kk*32 + lg*8
    bf16x8 bfr[2][4];
    const unsigned short* wk = wT + ((size_t)k << 14);
    #pragma unroll
    for (int ctl = 0; ctl < 2; ++ctl) {
      int crow = (wv * 2 + ctl) * 16 + l16;
      #pragma unroll
      for (int kk = 0; kk < 4; ++kk)
        bfr[ctl][kk] = *(const bf16x8*)(wk + crow * 128 + kk * 32 + lg * 8);
    }

    int T = (nt + 31) >> 5;
    for (int tt = 0; tt < T; ++tt) {
      int base = sbeg + tt * 32;

      unsigned int ea[2];
      bf16x8 af[2][4];
      #pragma unroll
      for (int rt = 0; rt < 2; ++rt) {
        int ar = base + rt * 16 + l16;
        ea[rt] = pl[ar < P ? ar : P - 1];
        const bf16x8* arow = (const bf16x8*)(xb + ((size_t)(ea[rt] >> 7) << 7) + lg * 8);
        #pragma unroll
        for (int kk = 0; kk < 4; ++kk) af[rt][kk] = arow[kk * 4];
      }

      f32x4 fr[2][2];
      #pragma unroll
      for (int rt = 0; rt < 2; ++rt)
        #pragma unroll
        for (int ctl = 0; ctl < 2; ++ctl)
          fr[rt][ctl] = (f32x4){0.f, 0.f, 0.f, 0.f};

      #pragma unroll
      for (int kk = 0; kk < 4; ++kk)
        #pragma unroll
        for (int rt = 0; rt < 2; ++rt)
          #pragma unroll
          for (int ctl = 0; ctl < 2; ++ctl)
            fr[rt][ctl] = __builtin_amdgcn_mfma_f32_16x16x32_bf16(
                af[rt][kk], bfr[ctl][kk], fr[rt][ctl], 0, 0, 0);

      // scatter into LDS accumulator; C layout: col=l&15, row=(l>>4)*4+i
      #pragma unroll
      for (int rt = 0; rt < 2; ++rt)
        #pragma unroll
        for (int i = 0; i < 4; ++i) {
          int r = base + rt * 16 + lg * 4 + i;
          unsigned int e2 = __shfl(ea[rt], lg * 4 + i, 64);
          if (r < send) {
            int lr = (int)(e2 & 127u);
            atomicAdd(&accs[lr * 128 + (wv * 2 + 0) * 16 + l16], fr[rt][0][i]);
            atomicAdd(&accs[lr * 128 + (wv * 2 + 1) * 16 + l16], fr[rt][1][i]);
          }
        }
    }
  }
  __syncthreads();

  // fused BN stats: per-channel sum / sumsq
  {
    int c = t & 127, rh = t >> 7;
    float s = 0.f, s2 = 0.f;
    #pragma unroll 4
    for (int j = 0; j < 64; ++j) {
      int r = rh * 64 + j;
      if (b * 128 + r < N) {
        float v = accs[r * 128 + c];
        s += v; s2 += v * v;
      }
    }
    atomicAdd(&stats[c], s);
    atomicAdd(&stats[128 + c], s2);
  }

  // writeout
  if (!BF16A) {
    float* ag = (float*)accg;
    #pragma unroll
    for (int j = 0; j < 16; ++j) {
      int idx = j * 256 + t;
      int row = idx >> 5;
      int n = b * 128 + row;
      if (n < N) {
        int c4 = (idx & 31) * 4;
        *(float4*)&ag[(size_t)n * 128 + c4] = *(const float4*)&accs[row * 128 + c4];
      }
    }
  } else {
    unsigned short* ag = (unsigned short*)accg;
    #pragma unroll
    for (int j = 0; j < 16; ++j) {
      int idx = j * 256 + t;
      int row = idx >> 5;
      int n = b * 128 + row;
      if (n < N) {
        int c4 = (idx & 31) * 4;
        const float* src = &accs[row * 128 + c4];
        ushort4v o = { f2bf(src[0]), f2bf(src[1]), f2bf(src[2]), f2bf(src[3]) };
        *(ushort4v*)&ag[(size_t)n * 128 + c4] = o;
      }
    }
  }
}

// ---- BN + ReLU -> bf16 ----
template<bool BF16A>
__global__ __launch_bounds__(256) void bn_relu_bf16_kernel(const void* __restrict__ in,
    const float* __restrict__ st, const float* __restrict__ gamma, const float* __restrict__ beta,
    unsigned short* __restrict__ out, int nvec, float invN)
{
  int stride = gridDim.x * blockDim.x;
  for (int i = blockIdx.x * blockDim.x + threadIdx.x; i < nvec; i += stride) {
    int cb = (i & 31) * 4;
    float vv[4];
    if constexpr (BF16A) {
      ushort4v u = ((const ushort4v*)in)[i];
      vv[0] = bf2f(u[0]); vv[1] = bf2f(u[1]); vv[2] = bf2f(u[2]); vv[3] = bf2f(u[3]);
    } else {
      float4 v = ((const float4*)in)[i];
      vv[0] = v.x; vv[1] = v.y; vv[2] = v.z; vv[3] = v.w;
    }
    ushort4v o;
    #pragma unroll
    for (int j = 0; j < 4; ++j) {
      int c = cb + j;
      float mean = st[c] * invN;
      float var = st[128 + c] * invN - mean * mean;
      float y = (vv[j] - mean) * rsqrtf(var + 1e-5f) * gamma[c] + beta[c];
      o[j] = f2bf(fmaxf(y, 0.f));
    }
    ((ushort4v*)out)[i] = o;
  }
}

// ---- BN + residual + ReLU -> f32 output ----
template<bool BF16A>
__global__ __launch_bounds__(256) void bn_add_relu_kernel(const void* __restrict__ in,
    const float* __restrict__ st, const float* __restrict__ gamma, const float* __restrict__ beta,
    const float* __restrict__ resid, float* __restrict__ out, int nvec, float invN)
{
  int stride = gridDim.x * blockDim.x;
  for (int i = blockIdx.x * blockDim.x + threadIdx.x; i < nvec; i += stride) {
    int cb = (i & 31) * 4;
    float vv[4];
    if constexpr (BF16A) {
      ushort4v u = ((const ushort4v*)in)[i];
      vv[0] = bf2f(u[0]); vv[1] = bf2f(u[1]); vv[2] = bf2f(u[2]); vv[3] = bf2f(u[3]);
    } else {
      float4 v = ((const float4*)in)[i];
      vv[0] = v.x; vv[1] = v.y; vv[2] = v.z; vv[3] = v.w;
    }
    float4 rz = ((const float4*)resid)[i];
    float rr[4] = {rz.x, rz.y, rz.z, rz.w};
    float ov[4];
    #pragma unroll
    for (int j = 0; j < 4; ++j) {
      int c = cb + j;
      float mean = st[c] * invN;
      float var = st[128 + c] * invN - mean * mean;
      float y = (vv[j] - mean) * rsqrtf(var + 1e-5f) * gamma[c] + beta[c] + rr[j];
      ov[j] = fmaxf(y, 0.f);
    }
    float4 o; o.x = ov[0]; o.y = ov[1]; o.z = ov[2]; o.w = ov[3];
    ((float4*)out)[i] = o;
  }
}

extern "C" void kernel_launch(void* const* d_in, const int* in_sizes, int n_in,
                              void* d_out, int out_size, void* d_ws, size_t ws_size,
                              hipStream_t stream) {
  const float* x  = (const float*)d_in[0];
  const float* w1 = (const float*)d_in[1];
  const float* g1 = (const float*)d_in[2];
  const float* b1 = (const float*)d_in[3];
  const float* w2 = (const float*)d_in[4];
  const float* g2 = (const float*)d_in[5];
  const float* b2 = (const float*)d_in[6];
  const int* iin  = (const int*)d_in[7];
  const int* iout = (const int*)d_in[8];

  const int C = 128;
  const int N = in_sizes[0] / C;          // 100000
  const int K = in_sizes[1] / (C * C);    // 27
  const int M = in_sizes[7] / K;          // 50000
  const int P = K * M;                    // 1,350,000
  const size_t nc = (size_t)N * C;
  const int wtot = K * C * C;
  const int nvec = (int)(nc / 4);
  const float invN = 1.0f / (float)N;

  const int NB = (N + 127) / 128;         // 782 output blocks
  const int BUCKETS = NB * K;             // 21114
  const int nb1 = (BUCKETS + 255) / 256;  // 83 (<=512)

  // ---- workspace layout (computed twice: f32 acc if it fits, else bf16) ----
  auto layout = [&](bool accf32, size_t* offs) -> size_t {
    size_t off = 0;
    auto alloc = [&](size_t bytes) { size_t o = off; off = (off + bytes + 255) & ~255ULL; return o; };
    offs[0] = alloc(nc * 2);                   // xb (conv input, bf16; reused for conv2 input)
    offs[1] = alloc((size_t)wtot * 2);         // w1T
    offs[2] = alloc((size_t)wtot * 2);         // w2T
    offs[3] = alloc(512 * 4);                  // stats
    offs[4] = alloc((size_t)BUCKETS * 4);      // counts
    offs[5] = alloc((size_t)BUCKETS * 4);      // segs
    offs[6] = alloc((size_t)BUCKETS * 4);      // cursor
    offs[7] = alloc(512 * 4);                  // bsums
    offs[8] = alloc((size_t)P * 4);            // pl (packed sorted pairs)
    offs[9] = alloc(nc * (accf32 ? 4 : 2));    // acc
    return off;
  };

  size_t offs[10];
  bool accf32 = true;
  if (layout(true, offs) > ws_size) { accf32 = false; layout(false, offs); }

  char* ws = (char*)d_ws;
  unsigned short* xb  = (unsigned short*)(ws + offs[0]);
  unsigned short* w1T = (unsigned short*)(ws + offs[1]);
  unsigned short* w2T = (unsigned short*)(ws + offs[2]);
  float* stats        = (float*)(ws + offs[3]);
  int* counts         = (int*)(ws + offs[4]);
  int* segs           = (int*)(ws + offs[5]);
  int* cursor         = (int*)(ws + offs[6]);
  int* bsums          = (int*)(ws + offs[7]);
  unsigned int* pl    = (unsigned int*)(ws + offs[8]);
  void* acc           = (void*)(ws + offs[9]);

  // ---- prep ----
  cast_x_kernel<<<2048, 256, 0, stream>>>(x, xb, nvec);
  wcast_kernel<<<(wtot + 255) / 256, 256, 0, stream>>>(w1, w1T, wtot);
  wcast_kernel<<<(wtot + 255) / 256, 256, 0, stream>>>(w2, w2T, wtot);
  hipMemsetAsync(stats, 0, 512 * 4, stream);
  hipMemsetAsync(counts, 0, (size_t)BUCKETS * 4, stream);

  // ---- sort pairs by (out_row>>7, k) ----
  hist_kernel<<<512, 256, 0, stream>>>(iout, counts, P, M, K);
  scan1_kernel<<<nb1, 256, 0, stream>>>(counts, segs, bsums, BUCKETS);
  scan2_kernel<<<1, 512, 0, stream>>>(bsums, nb1);
  scan3_kernel<<<nb1, 256, 0, stream>>>(segs, bsums, cursor, BUCKETS);
  rankscatter_kernel<<<512, 256, 0, stream>>>(iin, iout, cursor, pl, P, M, K);

  // ---- conv1 -> BN1 -> ReLU -> xb ----
  if (accf32) {
    spconv_os<false><<<NB, 256, 0, stream>>>(xb, w1T, pl, segs, acc, stats, N, K, P, BUCKETS);
    bn_relu_bf16_kernel<false><<<2048, 256, 0, stream>>>(acc, stats, g1, b1, xb, nvec, invN);
    spconv_os<false><<<NB, 256, 0, stream>>>(xb, w2T, pl, segs, acc, stats + 256, N, K, P, BUCKETS);
    bn_add_relu_kernel<false><<<2048, 256, 0, stream>>>(acc, stats + 256, g2, b2, x, (float*)d_out, nvec, invN);
  } else {
    spconv_os<true><<<NB, 256, 0, stream>>>(xb, w1T, pl, segs, acc, stats, N, K, P, BUCKETS);
    bn_relu_bf16_kernel<true><<<2048, 256, 0, stream>>>(acc, stats, g1, b1, xb, nvec, invN);
    spconv_os<true><<<NB, 256, 0, stream>>>(xb, w2T, pl, segs, acc, stats + 256, N, K, P, BUCKETS);
    bn_add_relu_kernel<true><<<2048, 256, 0, stream>>>(acc, stats + 256, g2, b2, x, (float*)d_out, nvec, invN);
  }
}

// Round 4
// 1405.533 us; speedup vs baseline: 1.9266x; 1.9266x over previous
//
#include <hip/hip_runtime.h>
#include <hip/hip_fp16.h>

typedef __bf16 bf16x8 __attribute__((ext_vector_type(8)));
typedef float f32x4 __attribute__((ext_vector_type(4)));
typedef unsigned short ushort4v __attribute__((ext_vector_type(4)));
typedef _Float16 h2v __attribute__((ext_vector_type(2)));

__device__ __forceinline__ unsigned short f2bf(float f) {
  unsigned int u = __builtin_bit_cast(unsigned int, f);
  u += 0x7FFFu + ((u >> 16) & 1u);   // round-to-nearest-even
  return (unsigned short)(u >> 16);
}
__device__ __forceinline__ float h2f(unsigned short u) {
  return (float)__builtin_bit_cast(_Float16, u);
}

// packed f16x2 atomic add (global_atomic_pk_add_f16); halves atomic op count
__device__ __forceinline__ void pk_atomic_add_f16(unsigned short* addr, float lo, float hi) {
  h2v v = { (_Float16)lo, (_Float16)hi };
#if __has_builtin(__builtin_amdgcn_global_atomic_fadd_v2f16)
  typedef h2v __attribute__((address_space(1))) *h2p;
  __builtin_amdgcn_global_atomic_fadd_v2f16((h2p)(unsigned long long)addr, v);
#elif __has_builtin(__builtin_amdgcn_flat_atomic_fadd_v2f16)
  __builtin_amdgcn_flat_atomic_fadd_v2f16((h2v*)addr, v);
#else
  unsafeAtomicAdd((__half2*)addr, *(__half2*)&v);
#endif
}

// ---- cast x (f32 -> bf16) ----
__global__ __launch_bounds__(256) void cast_x_kernel(const float* __restrict__ in,
                                                     unsigned short* __restrict__ out, int nvec) {
  int stride = gridDim.x * blockDim.x;
  for (int i = blockIdx.x * blockDim.x + threadIdx.x; i < nvec; i += stride) {
    float4 v = ((const float4*)in)[i];
    ushort4v o = { f2bf(v.x), f2bf(v.y), f2bf(v.z), f2bf(v.w) };
    ((ushort4v*)out)[i] = o;
  }
}

// ---- w [K][Cin][Cout] f32 -> wT [K][Cout][Cin] bf16 ----
__global__ __launch_bounds__(256) void wcast_kernel(const float* __restrict__ w,
                                                    unsigned short* __restrict__ wT, int total) {
  int i = blockIdx.x * blockDim.x + threadIdx.x;
  if (i >= total) return;
  int k = i >> 14, rem = i & 16383;
  int d = rem >> 7, c = rem & 127;
  wT[i] = f2bf(w[(k << 14) + (c << 7) + d]);
}

// ---- sparse conv: gather -> MFMA GEMM -> packed-f16 scatter-add ----
// grid: (ceil(M/128), K), block 256 (4 waves). Accumulator buffer is fp16.
__global__ __launch_bounds__(256) void spconv_pk(
    const unsigned short* __restrict__ xb, const unsigned short* __restrict__ wT,
    const int* __restrict__ iin, const int* __restrict__ iout,
    unsigned short* __restrict__ out, int M)
{
  __shared__ unsigned short xs[128 * 128];
  __shared__ unsigned short wsm[128 * 128];
  const int k = blockIdx.y;
  const int r0 = blockIdx.x * 128;
  const int t = threadIdx.x;

  // stage wT[k] (bf16 [cout][cin]) into LDS, swizzled
  {
    const char* wk = (const char*)(wT + ((size_t)k << 14));
    #pragma unroll
    for (int j = 0; j < 8; ++j) {
      int byte = (j * 256 + t) * 16;
      int swz = byte ^ (((byte >> 8) & 7) << 4);
      *(uint4*)((char*)wsm + swz) = *(const uint4*)(wk + byte);
    }
  }
  // gather 128 rows of x (bf16) into LDS, swizzled; 2 threads per row
  {
    int row = t >> 1, half = t & 1;
    int r = r0 + row;
    int idx = 0;
    if (r < M) idx = iin[k * M + r];
    const char* src = (const char*)(xb + ((size_t)idx << 7) + half * 64);
    #pragma unroll
    for (int j = 0; j < 8; ++j) {
      int byte = row * 256 + half * 128 + j * 16;
      int swz = byte ^ (((byte >> 8) & 7) << 4);
      *(uint4*)((char*)xs + swz) = *(const uint4*)(src + j * 16);
    }
  }
  __syncthreads();

  const int wv = t >> 6, l = t & 63;
  const int lrow = l & 15;
  const int kb = ((l >> 4) * 8) * 2;

  f32x4 acc[2][8];
  #pragma unroll
  for (int a = 0; a < 2; ++a)
    #pragma unroll
    for (int b = 0; b < 8; ++b)
      acc[a][b] = (f32x4){0.f, 0.f, 0.f, 0.f};

  #pragma unroll
  for (int kk = 0; kk < 4; ++kk) {
    int kbyte = kk * 64 + kb;
    bf16x8 af[2];
    #pragma unroll
    for (int rt = 0; rt < 2; ++rt) {
      int row = wv * 32 + rt * 16 + lrow;
      int byte = row * 256 + kbyte;
      af[rt] = *(const bf16x8*)((const char*)xs + (byte ^ ((row & 7) << 4)));
    }
    #pragma unroll
    for (int ct = 0; ct < 8; ++ct) {
      int crow = ct * 16 + lrow;
      int byte = crow * 256 + kbyte;
      bf16x8 bfr = *(const bf16x8*)((const char*)wsm + (byte ^ ((crow & 7) << 4)));
      acc[0][ct] = __builtin_amdgcn_mfma_f32_16x16x32_bf16(af[0], bfr, acc[0][ct], 0, 0, 0);
      acc[1][ct] = __builtin_amdgcn_mfma_f32_16x16x32_bf16(af[1], bfr, acc[1][ct], 0, 0, 0);
    }
  }

  // scatter-add: C layout col=lane&15, row=(lane>>4)*4+reg.
  // Adjacent channels live in adjacent lanes -> pair via shfl_xor(1), issue one
  // packed f16x2 atomic per channel pair. Even lanes take ct 0-3, odd ct 4-7.
  const int rbase = (l >> 4) * 4;
  const int colbase = (lrow & ~1);
  const bool evenlane = ((lrow & 1) == 0);
  #pragma unroll
  for (int rt = 0; rt < 2; ++rt) {
    #pragma unroll
    for (int i = 0; i < 4; ++i) {
      int prow = wv * 32 + rt * 16 + rbase + i;
      int r = r0 + prow;
      bool valid = (r < M);
      int orow = 0;
      if (valid) orow = iout[k * M + r];
      unsigned short* dst = out + ((size_t)orow << 7);
      #pragma unroll
      for (int ct = 0; ct < 8; ++ct) {
        float own = acc[rt][ct][i];
        float oth = __shfl_xor(own, 1, 64);      // all lanes participate
        bool mine = (evenlane == (ct < 4));
        if (valid && mine) {
          float lo = evenlane ? own : oth;
          float hi = evenlane ? oth : own;
          pk_atomic_add_f16(dst + ct * 16 + colbase, lo, hi);
        }
      }
    }
  }
}

// ---- BN stats: per-channel sum and sumsq over fp16 accumulator ----
__global__ __launch_bounds__(256) void bn_stats_kernel(const unsigned short* __restrict__ in,
                                                       float* __restrict__ st, int N) {
  int c = threadIdx.x & 127;
  int rh = threadIdx.x >> 7;
  float s = 0.f, s2 = 0.f;
  for (int r = blockIdx.x * 2 + rh; r < N; r += gridDim.x * 2) {
    float v = h2f(in[((size_t)r << 7) + c]);
    s += v; s2 += v * v;
  }
  atomicAdd(&st[c], s);
  atomicAdd(&st[128 + c], s2);
}

// ---- BN + ReLU -> bf16 (input to conv2) ----
__global__ __launch_bounds__(256) void bn_relu_bf16_kernel(const unsigned short* __restrict__ in,
    const float* __restrict__ st, const float* __restrict__ gamma, const float* __restrict__ beta,
    unsigned short* __restrict__ out, int nvec, float invN)
{
  int stride = gridDim.x * blockDim.x;
  for (int i = blockIdx.x * blockDim.x + threadIdx.x; i < nvec; i += stride) {
    int cb = (i & 31) * 4;
    ushort4v u = ((const ushort4v*)in)[i];
    ushort4v o;
    #pragma unroll
    for (int j = 0; j < 4; ++j) {
      int c = cb + j;
      float mean = st[c] * invN;
      float var = st[128 + c] * invN - mean * mean;
      float y = (h2f(u[j]) - mean) * rsqrtf(var + 1e-5f) * gamma[c] + beta[c];
      o[j] = f2bf(fmaxf(y, 0.f));
    }
    ((ushort4v*)out)[i] = o;
  }
}

// ---- BN + residual + ReLU -> f32 output ----
__global__ __launch_bounds__(256) void bn_add_relu_kernel(const unsigned short* __restrict__ in,
    const float* __restrict__ st, const float* __restrict__ gamma, const float* __restrict__ beta,
    const float* __restrict__ resid, float* __restrict__ out, int nvec, float invN)
{
  int stride = gridDim.x * blockDim.x;
  for (int i = blockIdx.x * blockDim.x + threadIdx.x; i < nvec; i += stride) {
    int cb = (i & 31) * 4;
    ushort4v u = ((const ushort4v*)in)[i];
    float4 rz = ((const float4*)resid)[i];
    float rr[4] = {rz.x, rz.y, rz.z, rz.w};
    float ov[4];
    #pragma unroll
    for (int j = 0; j < 4; ++j) {
      int c = cb + j;
      float mean = st[c] * invN;
      float var = st[128 + c] * invN - mean * mean;
      float y = (h2f(u[j]) - mean) * rsqrtf(var + 1e-5f) * gamma[c] + beta[c] + rr[j];
      ov[j] = fmaxf(y, 0.f);
    }
    float4 o; o.x = ov[0]; o.y = ov[1]; o.z = ov[2]; o.w = ov[3];
    ((float4*)out)[i] = o;
  }
}

extern "C" void kernel_launch(void* const* d_in, const int* in_sizes, int n_in,
                              void* d_out, int out_size, void* d_ws, size_t ws_size,
                              hipStream_t stream) {
  const float* x  = (const float*)d_in[0];
  const float* w1 = (const float*)d_in[1];
  const float* g1 = (const float*)d_in[2];
  const float* b1 = (const float*)d_in[3];
  const float* w2 = (const float*)d_in[4];
  const float* g2 = (const float*)d_in[5];
  const float* b2 = (const float*)d_in[6];
  const int* iin  = (const int*)d_in[7];
  const int* iout = (const int*)d_in[8];

  const int C = 128;
  const int N = in_sizes[0] / C;          // 100000
  const int K = in_sizes[1] / (C * C);    // 27
  const int M = in_sizes[7] / K;          // 50000
  const size_t nc = (size_t)N * C;
  const int wtot = K * C * C;
  const int nvec = (int)(nc / 4);
  const float invN = 1.0f / (float)N;

  // ---- workspace layout (~53 MB, well under the known-good 78.6 MB) ----
  size_t off = 0;
  auto alloc = [&](size_t bytes) { size_t o = off; off = (off + bytes + 255) & ~255ULL; return o; };
  char* ws = (char*)d_ws;
  size_t o_xb    = alloc(nc * 2);              // bf16 conv input
  size_t o_w1T   = alloc((size_t)wtot * 2);
  size_t o_w2T   = alloc((size_t)wtot * 2);
  size_t o_acc   = alloc(nc * 2);              // fp16 accumulator
  size_t o_stats = alloc(512 * 4);

  unsigned short* xb   = (unsigned short*)(ws + o_xb);
  unsigned short* w1T  = (unsigned short*)(ws + o_w1T);
  unsigned short* w2T  = (unsigned short*)(ws + o_w2T);
  unsigned short* accH = (unsigned short*)(ws + o_acc);
  float* stats         = (float*)(ws + o_stats);

  cast_x_kernel<<<2048, 256, 0, stream>>>(x, xb, nvec);
  wcast_kernel<<<(wtot + 255) / 256, 256, 0, stream>>>(w1, w1T, wtot);
  wcast_kernel<<<(wtot + 255) / 256, 256, 0, stream>>>(w2, w2T, wtot);
  hipMemsetAsync(stats, 0, 512 * 4, stream);
  hipMemsetAsync(accH, 0, nc * 2, stream);     // fp16 +0.0

  dim3 cgrid((M + 127) / 128, K);
  // conv1 -> accH (fp16, packed atomics)
  spconv_pk<<<cgrid, 256, 0, stream>>>(xb, w1T, iin, iout, accH, M);
  bn_stats_kernel<<<512, 256, 0, stream>>>(accH, stats, N);
  bn_relu_bf16_kernel<<<2048, 256, 0, stream>>>(accH, stats, g1, b1, xb, nvec, invN);
  // conv2 -> accH (re-zeroed)
  hipMemsetAsync(accH, 0, nc * 2, stream);
  spconv_pk<<<cgrid, 256, 0, stream>>>(xb, w2T, iin, iout, accH, M);
  bn_stats_kernel<<<512, 256, 0, stream>>>(accH, stats + 256, N);
  bn_add_relu_kernel<<<2048, 256, 0, stream>>>(accH, stats + 256, g2, b2, x, (float*)d_out, nvec, invN);
}